// Round 7
// baseline (384.295 us; speedup 1.0000x reference)
//
#include <hip/hip_runtime.h>

#define NN 50000
#define NE 800000
#define NNP 50176  // 392*128 = 196*256

// workspace offsets (bytes)
#define OFF_START 200704
#define OFF_BSUM  401408
#define OFF_S1    402432
#define OFF_S2    403456
#define OFF_WTT1  404480
#define OFF_WTT0  535552
#define OFF_WTC1  666624
#define OFF_WTC0  928768
#define OFF_RANK  1190912
#define OFF_COLW  4390912
#define OFF_XMB   10790912
#define OFF_AGG   36481024
#define OFF_XBF   62171136
// folded combine biases reuse the xmb region (xmb is dead after aggregate)
#define OFF_B1F   10790912
#define OFF_B0F   10791936

typedef __attribute__((ext_vector_type(4))) float f32x4;
typedef __bf16 bf16x8 __attribute__((ext_vector_type(8)));

__device__ __forceinline__ float bfu2f(unsigned short u) {
  return __uint_as_float(((unsigned)u) << 16);
}
__device__ __forceinline__ unsigned short f2bf(float f) {
  unsigned u = __float_as_uint(f);
  u += 0x7fffu + ((u >> 16) & 1u);
  return (unsigned short)(u >> 16);
}

// async global->LDS, 16B per lane; LDS dest is wave-uniform base + lane*16
__device__ __forceinline__ void gload16(const void* g, void* l) {
  __builtin_amdgcn_global_load_lds(
      (const __attribute__((address_space(1))) unsigned int*)g,
      (__attribute__((address_space(3))) unsigned int*)l, 16, 0, 0);
}

// ---------------- fused prep: count (3125) | x2bf (6272) | transpose (384) | aggb pad zero (22)
__global__ __launch_bounds__(256) void prep_kernel(
    const float* __restrict__ X, unsigned short* __restrict__ xbf,
    const int* __restrict__ ei, int* __restrict__ cnt, int* __restrict__ rank,
    const float* __restrict__ Wt1, const float* __restrict__ Wt0,
    const float* __restrict__ Wc1, const float* __restrict__ Wc0,
    unsigned short* __restrict__ WTt1, unsigned short* __restrict__ WTt0,
    unsigned short* __restrict__ WTc1, unsigned short* __restrict__ WTc0,
    unsigned short* __restrict__ aggb) {
  __shared__ unsigned short T[32 * 40];
  const int bid = blockIdx.x;
  const int t = threadIdx.x;
  if (bid < 3125) {  // count: rank[e] = old cnt[row]++
    const int e = bid * 256 + t;
    if (e < NE) rank[e] = atomicAdd(&cnt[ei[e]], 1);
    return;
  }
  if (bid < 3125 + 6272) {  // X fp32 -> bf16 (pad rows zeroed)
    const int gid = (bid - 3125) * 256 + t;
    const long base = (long)gid * 8;
    const int row = (int)(base >> 8);
    unsigned short o[8];
    if (row < NN) {
      f32x4 a = *(const f32x4*)(X + base);
      f32x4 b = *(const f32x4*)(X + base + 4);
#pragma unroll
      for (int i = 0; i < 4; i++) { o[i] = f2bf(a[i]); o[4 + i] = f2bf(b[i]); }
    } else {
#pragma unroll
      for (int i = 0; i < 8; i++) o[i] = 0;
    }
    *(uint4*)(xbf + base) = *(const uint4*)o;
    return;
  }
  if (bid < 3125 + 6272 + 384) {  // weight transpose: W[K][256] fp32 -> WT[256][K] bf16
    int tb = bid - (3125 + 6272);
    const float* W;
    unsigned short* WT;
    int K, kx, ny;
    if (tb < 64) { W = Wt1; WT = WTt1; K = 256; kx = tb & 7; ny = tb >> 3; }
    else if (tb < 128) { tb -= 64; W = Wt0; WT = WTt0; K = 256; kx = tb & 7; ny = tb >> 3; }
    else if (tb < 256) { tb -= 128; W = Wc1; WT = WTc1; K = 512; kx = tb & 15; ny = tb >> 4; }
    else { tb -= 256; W = Wc0; WT = WTc0; K = 512; kx = tb & 15; ny = tb >> 4; }
    const int k0 = kx * 32, n0 = ny * 32;
    const int kk = t >> 3, nn = (t & 7) * 4;
    f32x4 v = *(const f32x4*)(W + (k0 + kk) * 256 + n0 + nn);
#pragma unroll
    for (int i = 0; i < 4; i++) T[(nn + i) * 40 + kk] = f2bf(v[i]);
    __syncthreads();
    const int nn2 = t >> 3, kk2 = (t & 7) * 4;
    unsigned short o[4];
#pragma unroll
    for (int i = 0; i < 4; i++) o[i] = T[nn2 * 40 + kk2 + i];
    *(uint2*)(WT + (n0 + nn2) * K + k0 + kk2) = *(const uint2*)o;
    return;
  }
  // zero aggb pad rows [NN, NNP): 176*256 shorts = 5632 uint4
  const int idx = (bid - (3125 + 6272 + 384)) * 256 + t;
  if (idx < 5632) ((uint4*)(aggb + (size_t)NN * 256))[idx] = make_uint4(0, 0, 0, 0);
}

// ---------------- scan_all: merged scan1+scan2+scan3. Each block recomputes the 196
// chunk sums (L2-hit reads), scans them, then scans its own 256-chunk -> start.
__global__ __launch_bounds__(256) void scan_all(
    const int* __restrict__ cnt, int* __restrict__ start) {
  __shared__ int sd[256];
  __shared__ int pfx;
  const int t = threadIdx.x;
  const int bid = blockIdx.x;
  int s = 0;
  if (t < 196) {  // chunk-sum phase: thread t sums chunk t
    const int* p = cnt + t * 256;
    for (int j = 0; j < 256; j += 4) {
      int4 v = *(const int4*)(p + j);
      s += v.x + v.y + v.z + v.w;
    }
  }
  sd[t] = s;
  __syncthreads();
  for (int off = 1; off < 256; off <<= 1) {  // inclusive scan of chunk sums
    int y = (t >= off) ? sd[t - off] : 0;
    __syncthreads();
    sd[t] += y;
    __syncthreads();
  }
  if (t == 0) pfx = (bid == 0) ? 0 : sd[bid - 1];
  __syncthreads();
  const int row = bid * 256 + t;
  const int c = cnt[row];
  sd[t] = c;
  __syncthreads();
  for (int off = 1; off < 256; off <<= 1) {  // own-chunk scan
    int y = (t >= off) ? sd[t - off] : 0;
    __syncthreads();
    sd[t] += y;
    __syncthreads();
  }
  start[row] = pfx + sd[t] - c;  // exclusive
}

// ---------------- edge MLP helpers
__device__ __forceinline__ void mlp4(float a0, float a1, float a2, float a3,
                                     const f32x4* __restrict__ w,
                                     f32x4& h0, f32x4& h1, f32x4& h2, f32x4& h3,
                                     f32x4& h4, f32x4& h5, f32x4& h6, f32x4& h7) {
  h0 += w[0] * a0;  h1 += w[1] * a0;  h2 += w[2] * a0;  h3 += w[3] * a0;
  h4 += w[4] * a0;  h5 += w[5] * a0;  h6 += w[6] * a0;  h7 += w[7] * a0;
  h0 += w[8] * a1;  h1 += w[9] * a1;  h2 += w[10] * a1; h3 += w[11] * a1;
  h4 += w[12] * a1; h5 += w[13] * a1; h6 += w[14] * a1; h7 += w[15] * a1;
  h0 += w[16] * a2; h1 += w[17] * a2; h2 += w[18] * a2; h3 += w[19] * a2;
  h4 += w[20] * a2; h5 += w[21] * a2; h6 += w[22] * a2; h7 += w[23] * a2;
  h0 += w[24] * a3; h1 += w[25] * a3; h2 += w[26] * a3; h3 += w[27] * a3;
  h4 += w[28] * a3; h5 += w[29] * a3; h6 += w[30] * a3; h7 += w[31] * a3;
}

__device__ __forceinline__ float rdot(f32x4 h, f32x4 w) {
  float s = fmaxf(h[0], 0.0f) * w[0];
  s = fmaf(fmaxf(h[1], 0.0f), w[1], s);
  s = fmaf(fmaxf(h[2], 0.0f), w[2], s);
  s = fmaf(fmaxf(h[3], 0.0f), w[3], s);
  return s;
}

// ---------------- dual-panel bf16 GEMM, 128x128 tile, BK=64 (SH = 48KB scratch)
// 4 waves 2x2 -> each wave 64x64x2 panels; per K-step/wave: 24 ds_read_b128, 64 MFMA.
// 784 tasks = 8*98 -> bijective XCD swizzle. Staging keeps proven gload16+XOR pattern.
template <int KTOT, bool SPLIT, bool OUT_BF16>
__device__ __forceinline__ void gemm_tile(unsigned short* SH, int task,
    const unsigned short* __restrict__ A0, const unsigned short* __restrict__ A1,
    const unsigned short* __restrict__ WT1, const unsigned short* __restrict__ WT0,
    const float* __restrict__ bias1, const float* __restrict__ bias0,
    const int* __restrict__ mask, void* __restrict__ outp) {
  unsigned short* Al  = SH;            // 128*64
  unsigned short* B1l = SH + 8192;     // 128*64
  unsigned short* B0l = SH + 16384;    // 128*64
  const int t = threadIdx.x;
  const int swz = (task & 7) * 98 + (task >> 3);  // bijective over 784 = 8*98
  const int bx = swz & 1, by = swz >> 1;
  const int row0 = by * 128, col0 = bx * 128;
  const int wv = t >> 6, lane = t & 63, m = lane & 15, q = lane >> 4;
  const int wr = wv >> 1, wc = wv & 1;  // 2x2 wave grid: 64 rows x 64 cols each
  const int arow = t >> 3, ach = t & 7;
  f32x4 acc1[4][4], acc0[4][4];
#pragma unroll
  for (int rf = 0; rf < 4; rf++)
#pragma unroll
    for (int nt = 0; nt < 4; nt++) { acc1[rf][nt] = (f32x4)(0.0f); acc0[rf][nt] = (f32x4)(0.0f); }

  for (int k0 = 0; k0 < KTOT; k0 += 64) {
    const unsigned short* Ab;
    int kr;
    if constexpr (SPLIT) {
      if (k0 < 256) { Ab = A0; kr = k0; } else { Ab = A1; kr = k0 - 256; }
    } else { Ab = A0; kr = k0; }
#pragma unroll
    for (int i = 0; i < 4; i++) {  // A 128x64
      const int r = arow + i * 32;
      gload16(Ab + (size_t)(row0 + r) * 256 + kr + ((ach ^ (r & 7)) << 3),
              &Al[(i * 256 + t) * 8]);
    }
#pragma unroll
    for (int i = 0; i < 4; i++) {  // B panels 128x64 each
      const int r = arow + i * 32;
      const int sc = (ach ^ (r & 7)) << 3;
      gload16(WT1 + (size_t)(col0 + r) * KTOT + k0 + sc, &B1l[(i * 256 + t) * 8]);
      gload16(WT0 + (size_t)(col0 + r) * KTOT + k0 + sc, &B0l[(i * 256 + t) * 8]);
    }
    __syncthreads();
#pragma unroll
    for (int kk = 0; kk < 2; kk++) {
      bf16x8 af[4];
#pragma unroll
      for (int rf = 0; rf < 4; rf++) {
        const int r = wr * 64 + rf * 16 + m;
        af[rf] = *(const bf16x8*)&Al[r * 64 + (((kk * 4 + q) ^ (r & 7)) << 3)];
      }
#pragma unroll
      for (int nt = 0; nt < 4; nt++) {
        const int n = wc * 64 + nt * 16 + m;
        const int off = n * 64 + (((kk * 4 + q) ^ (n & 7)) << 3);
        bf16x8 f1 = *(const bf16x8*)&B1l[off];
        bf16x8 f0 = *(const bf16x8*)&B0l[off];
#pragma unroll
        for (int rf = 0; rf < 4; rf++) {
          acc1[rf][nt] = __builtin_amdgcn_mfma_f32_16x16x32_bf16(af[rf], f1, acc1[rf][nt], 0, 0, 0);
          acc0[rf][nt] = __builtin_amdgcn_mfma_f32_16x16x32_bf16(af[rf], f0, acc0[rf][nt], 0, 0, 0);
        }
      }
    }
    __syncthreads();
  }

#pragma unroll
  for (int rf = 0; rf < 4; rf++) {
    const int rbase = row0 + wr * 64 + rf * 16 + q * 4;
    int mk[4];
#pragma unroll
    for (int r = 0; r < 4; r++) mk[r] = (rbase + r < NN) ? mask[rbase + r] : 0;
#pragma unroll
    for (int nt = 0; nt < 4; nt++) {
      const int gc = col0 + wc * 64 + nt * 16 + m;
      const float bb1 = bias1[gc];
      const float bb0 = bias0[gc];
#pragma unroll
      for (int r = 0; r < 4; r++) {
        const int grr = rbase + r;
        if (grr < NN) {
          float v1 = acc1[rf][nt][r] + bb1;
          float v0 = acc0[rf][nt][r] + bb0;
          if constexpr (OUT_BF16) {
            v1 = fmaxf(v1, 0.0f);
            v0 = fmaxf(v0, 0.0f);
            float o = mk[r] ? (0.8f * v1 + 0.2f * v0) : (0.8f * v0 + 0.2f * v1);
            ((unsigned short*)outp)[(size_t)grr * 256 + gc] = f2bf(o);
          } else {
            float o = mk[r] ? (0.8f * v1 + 0.2f * v0) : (0.8f * v0 + 0.2f * v1);
            ((float*)outp)[(size_t)grr * 256 + gc] = o;
          }
        }
      }
    }
  }
}

// ---------------- midk: transform GEMM tiles (blocks 0..783) + edge MLP fill (784..3908)
__global__ __launch_bounds__(256, 2) void midk(
    const unsigned short* __restrict__ xbf,
    const unsigned short* __restrict__ WTt1, const unsigned short* __restrict__ WTt0,
    const float* __restrict__ bt1, const float* __restrict__ bt0,
    const int* __restrict__ msk, unsigned short* __restrict__ xmb,
    const float* __restrict__ ea,
    const float* __restrict__ Wm1, const float* __restrict__ bm1,
    const float* __restrict__ Wm2, const float* __restrict__ bm2,
    const int* __restrict__ ei, const int* __restrict__ start,
    const int* __restrict__ rank, uint2* __restrict__ colw) {
  __shared__ __align__(16) unsigned short SH[3 * 128 * 64];  // 48KB
  const int bid = blockIdx.x;
  const int t = threadIdx.x;
  if (bid < 784) {
    gemm_tile<256, false, true>(SH, bid, xbf, (const unsigned short*)nullptr,
                                WTt1, WTt0, bt1, bt0, msk, xmb);
    return;
  }
  // ---- edge MLP + CSR fill (shared aliased onto SH)
  float* w1 = (float*)SH;         // 512
  float* b1 = w1 + 512;           // 32
  float* w2 = b1 + 32;            // 32
  float* b2s = w2 + 32;           // 1
  w1[t] = Wm1[t];
  w1[t + 256] = Wm1[t + 256];
  if (t < 32) { b1[t] = bm1[t]; w2[t] = Wm2[t]; }
  if (t == 0) b2s[0] = bm2[0];
  __syncthreads();
  const int e = (bid - 784) * 256 + t;
  if (e >= NE) return;
  f32x4 r0 = *(const f32x4*)(ea + e * 16);
  f32x4 r1 = *(const f32x4*)(ea + e * 16 + 4);
  f32x4 r2 = *(const f32x4*)(ea + e * 16 + 8);
  f32x4 r3 = *(const f32x4*)(ea + e * 16 + 12);
  const f32x4* bv = (const f32x4*)b1;
  f32x4 h0 = bv[0], h1 = bv[1], h2 = bv[2], h3 = bv[3];
  f32x4 h4 = bv[4], h5 = bv[5], h6 = bv[6], h7 = bv[7];
  const f32x4* wv = (const f32x4*)w1;
  mlp4(r0[0], r0[1], r0[2], r0[3], wv, h0, h1, h2, h3, h4, h5, h6, h7);
  mlp4(r1[0], r1[1], r1[2], r1[3], wv + 32, h0, h1, h2, h3, h4, h5, h6, h7);
  mlp4(r2[0], r2[1], r2[2], r2[3], wv + 64, h0, h1, h2, h3, h4, h5, h6, h7);
  mlp4(r3[0], r3[1], r3[2], r3[3], wv + 96, h0, h1, h2, h3, h4, h5, h6, h7);
  const f32x4* w2v = (const f32x4*)w2;
  float s = b2s[0];
  s += rdot(h0, w2v[0]) + rdot(h1, w2v[1]) + rdot(h2, w2v[2]) + rdot(h3, w2v[3]);
  s += rdot(h4, w2v[4]) + rdot(h5, w2v[5]) + rdot(h6, w2v[6]) + rdot(h7, w2v[7]);
  const float sp = (s > 0.0f) ? (s + log1pf(expf(-s))) : log1pf(expf(s));
  uint2 p;
  p.x = (unsigned)ei[NE + e];
  p.y = __float_as_uint(sp);
  colw[start[ei[e]] + rank[e]] = p;
}

// ---------------- combine GEMM wrapper (reads aggb directly; norm folded into weights)
__global__ __launch_bounds__(256, 2) void gemm_combine(
    const unsigned short* __restrict__ aggb, const unsigned short* __restrict__ xbf,
    const unsigned short* __restrict__ WT1, const unsigned short* __restrict__ WT0,
    const float* __restrict__ bias1, const float* __restrict__ bias0,
    const int* __restrict__ mask, float* __restrict__ out) {
  __shared__ __align__(16) unsigned short SH[3 * 128 * 64];
  gemm_tile<512, true, false>(SH, blockIdx.x, aggb, xbf, WT1, WT0, bias1, bias0, mask, out);
}

// ---------------- pull aggregation (R3-proven: one wave/row, 8 edges in flight; NO stats)
#define EDGE(u, wgt) do { \
  dsum += wgt; \
  acc[0] = fmaf(wgt, __uint_as_float(u.x << 16), acc[0]); \
  acc[1] = fmaf(wgt, __uint_as_float(u.x & 0xffff0000u), acc[1]); \
  acc[2] = fmaf(wgt, __uint_as_float(u.y << 16), acc[2]); \
  acc[3] = fmaf(wgt, __uint_as_float(u.y & 0xffff0000u), acc[3]); \
} while (0)

__global__ __launch_bounds__(256) void aggregate_kernel(
    const int* __restrict__ start, const int* __restrict__ cnt,
    const uint2* __restrict__ colw,
    const unsigned short* __restrict__ xmb, unsigned short* __restrict__ aggb) {
  const int wave = threadIdx.x >> 6, lane = threadIdx.x & 63;
  const int row = blockIdx.x * 4 + wave;
  const int s = start[row];
  const int c = cnt[row];
  const int choff = lane * 4;
  f32x4 acc = (f32x4)(0.0f);
  float dsum = 0.0f;
  int i = 0;
  for (; i + 8 <= c; i += 8) {  // 8 edges in flight
    uint2 cw0 = colw[s + i],     cw1 = colw[s + i + 1];
    uint2 cw2 = colw[s + i + 2], cw3 = colw[s + i + 3];
    uint2 cw4 = colw[s + i + 4], cw5 = colw[s + i + 5];
    uint2 cw6 = colw[s + i + 6], cw7 = colw[s + i + 7];
    uint2 u0 = *(const uint2*)(xmb + (size_t)cw0.x * 256 + choff);
    uint2 u1 = *(const uint2*)(xmb + (size_t)cw1.x * 256 + choff);
    uint2 u2 = *(const uint2*)(xmb + (size_t)cw2.x * 256 + choff);
    uint2 u3 = *(const uint2*)(xmb + (size_t)cw3.x * 256 + choff);
    uint2 u4 = *(const uint2*)(xmb + (size_t)cw4.x * 256 + choff);
    uint2 u5 = *(const uint2*)(xmb + (size_t)cw5.x * 256 + choff);
    uint2 u6 = *(const uint2*)(xmb + (size_t)cw6.x * 256 + choff);
    uint2 u7 = *(const uint2*)(xmb + (size_t)cw7.x * 256 + choff);
    EDGE(u0, __uint_as_float(cw0.y));
    EDGE(u1, __uint_as_float(cw1.y));
    EDGE(u2, __uint_as_float(cw2.y));
    EDGE(u3, __uint_as_float(cw3.y));
    EDGE(u4, __uint_as_float(cw4.y));
    EDGE(u5, __uint_as_float(cw5.y));
    EDGE(u6, __uint_as_float(cw6.y));
    EDGE(u7, __uint_as_float(cw7.y));
  }
  for (; i + 4 <= c; i += 4) {
    uint2 cw0 = colw[s + i],     cw1 = colw[s + i + 1];
    uint2 cw2 = colw[s + i + 2], cw3 = colw[s + i + 3];
    uint2 u0 = *(const uint2*)(xmb + (size_t)cw0.x * 256 + choff);
    uint2 u1 = *(const uint2*)(xmb + (size_t)cw1.x * 256 + choff);
    uint2 u2 = *(const uint2*)(xmb + (size_t)cw2.x * 256 + choff);
    uint2 u3 = *(const uint2*)(xmb + (size_t)cw3.x * 256 + choff);
    EDGE(u0, __uint_as_float(cw0.y));
    EDGE(u1, __uint_as_float(cw1.y));
    EDGE(u2, __uint_as_float(cw2.y));
    EDGE(u3, __uint_as_float(cw3.y));
  }
  for (; i < c; i++) {
    uint2 cw0 = colw[s + i];
    uint2 u0 = *(const uint2*)(xmb + (size_t)cw0.x * 256 + choff);
    EDGE(u0, __uint_as_float(cw0.y));
  }
  float d = (dsum < 0.5f) ? dsum + 1.0f : dsum;
  const float inv = 1.0f / d;
  unsigned short o[4];
#pragma unroll
  for (int j = 0; j < 4; j++) o[j] = f2bf(acc[j] * inv);
  *(uint2*)(aggb + (size_t)row * 256 + choff) = *(const uint2*)o;
}

// ---------------- per-channel sums for GraphNorm (separate pass: depth-250 atomic chains)
__global__ __launch_bounds__(256) void stats_kernel(
    const unsigned short* __restrict__ aggb, float* __restrict__ S1, float* __restrict__ S2) {
  const int c = threadIdx.x;
  const int r0 = blockIdx.x * 200;
  float s1 = 0.0f, s2 = 0.0f;
  for (int r = 0; r < 200; r++) {
    float v = bfu2f(aggb[(size_t)(r0 + r) * 256 + c]);
    s1 += v;
    s2 = fmaf(v, v, s2);
  }
  unsafeAtomicAdd(&S1[c], s1);
  unsafeAtomicAdd(&S2[c], s2);
}

// ---------------- fold GraphNorm into combine weights/biases:
// WTc'[n][k<256] = sc_k * WTc[n][k];  bias'[n] = bc[n] + sum_k sh_k * Wc[k][n] (fp32)
__global__ __launch_bounds__(256) void fold_kernel(
    const float* __restrict__ S1, const float* __restrict__ S2,
    const float* __restrict__ gnw, const float* __restrict__ gnb,
    const float* __restrict__ gna,
    const float* __restrict__ Wc1, const float* __restrict__ Wc0,
    const float* __restrict__ bc1, const float* __restrict__ bc0,
    unsigned short* __restrict__ WTc1, unsigned short* __restrict__ WTc0,
    float* __restrict__ b1f, float* __restrict__ b0f) {
  __shared__ float r1[256];
  __shared__ float r0[256];
  const int n = blockIdx.x, t = threadIdx.x;
  const float inv_n = 1.0f / (float)NN;
  const float mean = S1[t] * inv_n;
  const float ex2 = S2[t] * inv_n;
  const float am = gna[t] * mean;
  const float var = ex2 - 2.0f * am * mean + am * am;
  const float sc = gnw[t] * rsqrtf(var + 1e-5f);
  const float sh = gnb[t] - sc * am;
  const float w1 = bfu2f(WTc1[n * 512 + t]);
  WTc1[n * 512 + t] = f2bf(w1 * sc);
  const float w0 = bfu2f(WTc0[n * 512 + t]);
  WTc0[n * 512 + t] = f2bf(w0 * sc);
  r1[t] = sh * Wc1[t * 256 + n];
  r0[t] = sh * Wc0[t * 256 + n];
  __syncthreads();
  for (int off = 128; off > 0; off >>= 1) {
    if (t < off) { r1[t] += r1[t + off]; r0[t] += r0[t + off]; }
    __syncthreads();
  }
  if (t == 0) {
    b1f[n] = bc1[n] + r1[0];
    b0f[n] = bc0[n] + r0[0];
  }
}

extern "C" void kernel_launch(void* const* d_in, const int* in_sizes, int n_in,
                              void* d_out, int out_size, void* d_ws, size_t ws_size,
                              hipStream_t stream) {
  (void)in_sizes; (void)n_in; (void)out_size; (void)ws_size;
  const float* x   = (const float*)d_in[0];
  const int*   ei  = (const int*)d_in[1];
  const int*   msk = (const int*)d_in[3];
  const float* ea  = (const float*)d_in[4];
  const float* Wt0 = (const float*)d_in[5];
  const float* bt0 = (const float*)d_in[6];
  const float* Wt1 = (const float*)d_in[7];
  const float* bt1 = (const float*)d_in[8];
  const float* Wc0 = (const float*)d_in[9];
  const float* bc0 = (const float*)d_in[10];
  const float* Wc1 = (const float*)d_in[11];
  const float* bc1 = (const float*)d_in[12];
  const float* gnw = (const float*)d_in[13];
  const float* gnb = (const float*)d_in[14];
  const float* gna = (const float*)d_in[15];
  const float* Wm1 = (const float*)d_in[16];
  const float* bm1 = (const float*)d_in[17];
  const float* Wm2 = (const float*)d_in[18];
  const float* bm2 = (const float*)d_in[19];

  char* ws = (char*)d_ws;
  int* cnt      = (int*)ws;
  int* startA   = (int*)(ws + OFF_START);
  float* S1     = (float*)(ws + OFF_S1);
  float* S2     = (float*)(ws + OFF_S2);
  unsigned short* WTt1 = (unsigned short*)(ws + OFF_WTT1);
  unsigned short* WTt0 = (unsigned short*)(ws + OFF_WTT0);
  unsigned short* WTc1 = (unsigned short*)(ws + OFF_WTC1);
  unsigned short* WTc0 = (unsigned short*)(ws + OFF_WTC0);
  int* rankA    = (int*)(ws + OFF_RANK);
  uint2* colw   = (uint2*)(ws + OFF_COLW);
  unsigned short* xmb  = (unsigned short*)(ws + OFF_XMB);
  unsigned short* aggb = (unsigned short*)(ws + OFF_AGG);
  unsigned short* xbf  = (unsigned short*)(ws + OFF_XBF);
  float* b1f = (float*)(ws + OFF_B1F);  // reuses xmb region (dead after aggregate)
  float* b0f = (float*)(ws + OFF_B0F);

  hipMemsetAsync(ws, 0, 404480, stream);  // cnt + start + blockSum + S1/S2

  prep_kernel<<<9803, 256, 0, stream>>>(x, xbf, ei, cnt, rankA,
                                        Wt1, Wt0, Wc1, Wc0,
                                        WTt1, WTt0, WTc1, WTc0, aggb);
  scan_all<<<196, 256, 0, stream>>>(cnt, startA);
  midk<<<3909, 256, 0, stream>>>(xbf, WTt1, WTt0, bt1, bt0, msk, xmb,
                                 ea, Wm1, bm1, Wm2, bm2, ei, startA, rankA, colw);
  aggregate_kernel<<<12500, 256, 0, stream>>>(startA, cnt, colw, xmb, aggb);
  stats_kernel<<<250, 256, 0, stream>>>(aggb, S1, S2);
  fold_kernel<<<256, 256, 0, stream>>>(S1, S2, gnw, gnb, gna, Wc1, Wc0, bc1, bc0,
                                       WTc1, WTc0, b1f, b0f);
  gemm_combine<<<784, 256, 0, stream>>>(aggb, xbf, WTc1, WTc0, b1f, b0f,
                                        msk, (float*)d_out);
}

// Round 8
// 375.850 us; speedup vs baseline: 1.0225x; 1.0225x over previous
//
#include <hip/hip_runtime.h>

#define NN 50000
#define NE 800000
#define NNP 50176  // 392*128 = 196*256

// workspace offsets (bytes)
#define OFF_START 200704
#define OFF_BSUM  401408
#define OFF_S1    402432
#define OFF_S2    403456
#define OFF_WTT1  404480
#define OFF_WTT0  535552
#define OFF_WTC1  666624
#define OFF_WTC0  928768
#define OFF_RANK  1190912
#define OFF_COLW  4390912
#define OFF_XMB   10790912
#define OFF_AGG   36481024
#define OFF_XBF   62171136
// folded combine biases reuse the xmb region (xmb is dead after aggregate)
#define OFF_B1F   10790912
#define OFF_B0F   10791936

typedef __attribute__((ext_vector_type(4))) float f32x4;
typedef __bf16 bf16x8 __attribute__((ext_vector_type(8)));

__device__ __forceinline__ float bfu2f(unsigned short u) {
  return __uint_as_float(((unsigned)u) << 16);
}
__device__ __forceinline__ unsigned short f2bf(float f) {
  unsigned u = __float_as_uint(f);
  u += 0x7fffu + ((u >> 16) & 1u);
  return (unsigned short)(u >> 16);
}

// async global->LDS, 16B per lane; LDS dest is wave-uniform base + lane*16
__device__ __forceinline__ void gload16(const void* g, void* l) {
  __builtin_amdgcn_global_load_lds(
      (const __attribute__((address_space(1))) unsigned int*)g,
      (__attribute__((address_space(3))) unsigned int*)l, 16, 0, 0);
}

// ---------------- fused prep: count (3125) | x2bf (6272) | transpose (384) | aggb pad zero (22)
__global__ __launch_bounds__(256) void prep_kernel(
    const float* __restrict__ X, unsigned short* __restrict__ xbf,
    const int* __restrict__ ei, int* __restrict__ cnt, int* __restrict__ rank,
    const float* __restrict__ Wt1, const float* __restrict__ Wt0,
    const float* __restrict__ Wc1, const float* __restrict__ Wc0,
    unsigned short* __restrict__ WTt1, unsigned short* __restrict__ WTt0,
    unsigned short* __restrict__ WTc1, unsigned short* __restrict__ WTc0,
    unsigned short* __restrict__ aggb) {
  __shared__ unsigned short T[32 * 40];
  const int bid = blockIdx.x;
  const int t = threadIdx.x;
  if (bid < 3125) {  // count: rank[e] = old cnt[row]++
    const int e = bid * 256 + t;
    if (e < NE) rank[e] = atomicAdd(&cnt[ei[e]], 1);
    return;
  }
  if (bid < 3125 + 6272) {  // X fp32 -> bf16 (pad rows zeroed)
    const int gid = (bid - 3125) * 256 + t;
    const long base = (long)gid * 8;
    const int row = (int)(base >> 8);
    unsigned short o[8];
    if (row < NN) {
      f32x4 a = *(const f32x4*)(X + base);
      f32x4 b = *(const f32x4*)(X + base + 4);
#pragma unroll
      for (int i = 0; i < 4; i++) { o[i] = f2bf(a[i]); o[4 + i] = f2bf(b[i]); }
    } else {
#pragma unroll
      for (int i = 0; i < 8; i++) o[i] = 0;
    }
    *(uint4*)(xbf + base) = *(const uint4*)o;
    return;
  }
  if (bid < 3125 + 6272 + 384) {  // weight transpose: W[K][256] fp32 -> WT[256][K] bf16
    int tb = bid - (3125 + 6272);
    const float* W;
    unsigned short* WT;
    int K, kx, ny;
    if (tb < 64) { W = Wt1; WT = WTt1; K = 256; kx = tb & 7; ny = tb >> 3; }
    else if (tb < 128) { tb -= 64; W = Wt0; WT = WTt0; K = 256; kx = tb & 7; ny = tb >> 3; }
    else if (tb < 256) { tb -= 128; W = Wc1; WT = WTc1; K = 512; kx = tb & 15; ny = tb >> 4; }
    else { tb -= 256; W = Wc0; WT = WTc0; K = 512; kx = tb & 15; ny = tb >> 4; }
    const int k0 = kx * 32, n0 = ny * 32;
    const int kk = t >> 3, nn = (t & 7) * 4;
    f32x4 v = *(const f32x4*)(W + (k0 + kk) * 256 + n0 + nn);
#pragma unroll
    for (int i = 0; i < 4; i++) T[(nn + i) * 40 + kk] = f2bf(v[i]);
    __syncthreads();
    const int nn2 = t >> 3, kk2 = (t & 7) * 4;
    unsigned short o[4];
#pragma unroll
    for (int i = 0; i < 4; i++) o[i] = T[nn2 * 40 + kk2 + i];
    *(uint2*)(WT + (n0 + nn2) * K + k0 + kk2) = *(const uint2*)o;
    return;
  }
  // zero aggb pad rows [NN, NNP): 176*256 shorts = 5632 uint4
  const int idx = (bid - (3125 + 6272 + 384)) * 256 + t;
  if (idx < 5632) ((uint4*)(aggb + (size_t)NN * 256))[idx] = make_uint4(0, 0, 0, 0);
}

// ---------------- scan_all: merged scan1+scan2+scan3. Each block recomputes the 196
// chunk sums (L2-hit reads), scans them, then scans its own 256-chunk -> start.
__global__ __launch_bounds__(256) void scan_all(
    const int* __restrict__ cnt, int* __restrict__ start) {
  __shared__ int sd[256];
  __shared__ int pfx;
  const int t = threadIdx.x;
  const int bid = blockIdx.x;
  int s = 0;
  if (t < 196) {  // chunk-sum phase: thread t sums chunk t
    const int* p = cnt + t * 256;
    for (int j = 0; j < 256; j += 4) {
      int4 v = *(const int4*)(p + j);
      s += v.x + v.y + v.z + v.w;
    }
  }
  sd[t] = s;
  __syncthreads();
  for (int off = 1; off < 256; off <<= 1) {  // inclusive scan of chunk sums
    int y = (t >= off) ? sd[t - off] : 0;
    __syncthreads();
    sd[t] += y;
    __syncthreads();
  }
  if (t == 0) pfx = (bid == 0) ? 0 : sd[bid - 1];
  __syncthreads();
  const int row = bid * 256 + t;
  const int c = cnt[row];
  sd[t] = c;
  __syncthreads();
  for (int off = 1; off < 256; off <<= 1) {  // own-chunk scan
    int y = (t >= off) ? sd[t - off] : 0;
    __syncthreads();
    sd[t] += y;
    __syncthreads();
  }
  start[row] = pfx + sd[t] - c;  // exclusive
}

// ---------------- edge MLP helpers
__device__ __forceinline__ void mlp4(float a0, float a1, float a2, float a3,
                                     const f32x4* __restrict__ w,
                                     f32x4& h0, f32x4& h1, f32x4& h2, f32x4& h3,
                                     f32x4& h4, f32x4& h5, f32x4& h6, f32x4& h7) {
  h0 += w[0] * a0;  h1 += w[1] * a0;  h2 += w[2] * a0;  h3 += w[3] * a0;
  h4 += w[4] * a0;  h5 += w[5] * a0;  h6 += w[6] * a0;  h7 += w[7] * a0;
  h0 += w[8] * a1;  h1 += w[9] * a1;  h2 += w[10] * a1; h3 += w[11] * a1;
  h4 += w[12] * a1; h5 += w[13] * a1; h6 += w[14] * a1; h7 += w[15] * a1;
  h0 += w[16] * a2; h1 += w[17] * a2; h2 += w[18] * a2; h3 += w[19] * a2;
  h4 += w[20] * a2; h5 += w[21] * a2; h6 += w[22] * a2; h7 += w[23] * a2;
  h0 += w[24] * a3; h1 += w[25] * a3; h2 += w[26] * a3; h3 += w[27] * a3;
  h4 += w[28] * a3; h5 += w[29] * a3; h6 += w[30] * a3; h7 += w[31] * a3;
}

__device__ __forceinline__ float rdot(f32x4 h, f32x4 w) {
  float s = fmaxf(h[0], 0.0f) * w[0];
  s = fmaf(fmaxf(h[1], 0.0f), w[1], s);
  s = fmaf(fmaxf(h[2], 0.0f), w[2], s);
  s = fmaf(fmaxf(h[3], 0.0f), w[3], s);
  return s;
}

// ---------------- dual-panel bf16 GEMM tile body (R6-proven 128x64, BK=64, 32KB LDS)
// 4 waves 2x2; per K-step/wave: 16 ds_read_b128, 32 MFMA; 3 blocks/CU co-residency
// is the binding resource (R7 A/B: 48KB tile @2/CU regressed 8%).
template <int KTOT, bool SPLIT, bool OUT_BF16>
__device__ __forceinline__ void gemm_tile(unsigned short* SH, int task,
    const unsigned short* __restrict__ A0, const unsigned short* __restrict__ A1,
    const unsigned short* __restrict__ WT1, const unsigned short* __restrict__ WT0,
    const float* __restrict__ bias1, const float* __restrict__ bias0,
    const int* __restrict__ mask, void* __restrict__ outp) {
  unsigned short* Al  = SH;           // 128*64
  unsigned short* B1l = SH + 8192;    // 64*64
  unsigned short* B0l = SH + 12288;   // 64*64
  const int t = threadIdx.x;
  const int swz = (task & 7) * 196 + (task >> 3);  // bijective XCD swizzle over 1568
  const int bx = swz & 3, by = swz >> 2;
  const int row0 = by * 128, col0 = bx * 64;
  const int wv = t >> 6, lane = t & 63, m = lane & 15, q = lane >> 4;
  const int wr = wv >> 1, wc = wv & 1;
  const int arow = t >> 3, ach = t & 7;
  f32x4 acc1[4][2], acc0[4][2];
#pragma unroll
  for (int rf = 0; rf < 4; rf++)
#pragma unroll
    for (int nt = 0; nt < 2; nt++) { acc1[rf][nt] = (f32x4)(0.0f); acc0[rf][nt] = (f32x4)(0.0f); }

  for (int k0 = 0; k0 < KTOT; k0 += 64) {
    const unsigned short* Ab;
    int kr;
    if constexpr (SPLIT) {
      if (k0 < 256) { Ab = A0; kr = k0; } else { Ab = A1; kr = k0 - 256; }
    } else { Ab = A0; kr = k0; }
#pragma unroll
    for (int i = 0; i < 4; i++) {
      const int r = arow + i * 32;
      gload16(Ab + (size_t)(row0 + r) * 256 + kr + ((ach ^ (r & 7)) << 3),
              &Al[(i * 256 + t) * 8]);
    }
#pragma unroll
    for (int i = 0; i < 2; i++) {
      const int r = arow + i * 32;
      const int sc = (ach ^ (r & 7)) << 3;
      gload16(WT1 + (size_t)(col0 + r) * KTOT + k0 + sc, &B1l[(i * 256 + t) * 8]);
      gload16(WT0 + (size_t)(col0 + r) * KTOT + k0 + sc, &B0l[(i * 256 + t) * 8]);
    }
    __syncthreads();
#pragma unroll
    for (int kk = 0; kk < 2; kk++) {
      bf16x8 af[4];
#pragma unroll
      for (int rf = 0; rf < 4; rf++) {
        const int r = wr * 64 + rf * 16 + m;
        af[rf] = *(const bf16x8*)&Al[r * 64 + (((kk * 4 + q) ^ (r & 7)) << 3)];
      }
#pragma unroll
      for (int nt = 0; nt < 2; nt++) {
        const int n = wc * 32 + nt * 16 + m;
        const int off = n * 64 + (((kk * 4 + q) ^ (n & 7)) << 3);
        bf16x8 f1 = *(const bf16x8*)&B1l[off];
        bf16x8 f0 = *(const bf16x8*)&B0l[off];
#pragma unroll
        for (int rf = 0; rf < 4; rf++) {
          acc1[rf][nt] = __builtin_amdgcn_mfma_f32_16x16x32_bf16(af[rf], f1, acc1[rf][nt], 0, 0, 0);
          acc0[rf][nt] = __builtin_amdgcn_mfma_f32_16x16x32_bf16(af[rf], f0, acc0[rf][nt], 0, 0, 0);
        }
      }
    }
    __syncthreads();
  }

#pragma unroll
  for (int rf = 0; rf < 4; rf++) {
    const int rbase = row0 + wr * 64 + rf * 16 + q * 4;
    int mk[4];
#pragma unroll
    for (int r = 0; r < 4; r++) mk[r] = (rbase + r < NN) ? mask[rbase + r] : 0;
#pragma unroll
    for (int nt = 0; nt < 2; nt++) {
      const int gc = col0 + wc * 32 + nt * 16 + m;
      const float bb1 = bias1[gc];
      const float bb0 = bias0[gc];
#pragma unroll
      for (int r = 0; r < 4; r++) {
        const int grr = rbase + r;
        if (grr < NN) {
          float v1 = acc1[rf][nt][r] + bb1;
          float v0 = acc0[rf][nt][r] + bb0;
          if constexpr (OUT_BF16) {
            v1 = fmaxf(v1, 0.0f);
            v0 = fmaxf(v0, 0.0f);
            float o = mk[r] ? (0.8f * v1 + 0.2f * v0) : (0.8f * v0 + 0.2f * v1);
            ((unsigned short*)outp)[(size_t)grr * 256 + gc] = f2bf(o);
          } else {
            float o = mk[r] ? (0.8f * v1 + 0.2f * v0) : (0.8f * v0 + 0.2f * v1);
            ((float*)outp)[(size_t)grr * 256 + gc] = o;
          }
        }
      }
    }
  }
}

// ---------------- midk: transform GEMM tiles (blocks 0..1567) + edge MLP fill (1568..4692)
__global__ __launch_bounds__(256, 3) void midk(
    const unsigned short* __restrict__ xbf,
    const unsigned short* __restrict__ WTt1, const unsigned short* __restrict__ WTt0,
    const float* __restrict__ bt1, const float* __restrict__ bt0,
    const int* __restrict__ msk, unsigned short* __restrict__ xmb,
    const float* __restrict__ ea,
    const float* __restrict__ Wm1, const float* __restrict__ bm1,
    const float* __restrict__ Wm2, const float* __restrict__ bm2,
    const int* __restrict__ ei, const int* __restrict__ start,
    const int* __restrict__ rank, uint2* __restrict__ colw) {
  __shared__ __align__(16) unsigned short SH[128 * 64 + 64 * 64 + 64 * 64];  // 32KB
  const int bid = blockIdx.x;
  const int t = threadIdx.x;
  if (bid < 1568) {
    gemm_tile<256, false, true>(SH, bid, xbf, (const unsigned short*)nullptr,
                                WTt1, WTt0, bt1, bt0, msk, xmb);
    return;
  }
  // ---- edge MLP + CSR fill (shared aliased onto SH)
  float* w1 = (float*)SH;         // 512
  float* b1 = w1 + 512;           // 32
  float* w2 = b1 + 32;            // 32
  float* b2s = w2 + 32;           // 1
  w1[t] = Wm1[t];
  w1[t + 256] = Wm1[t + 256];
  if (t < 32) { b1[t] = bm1[t]; w2[t] = Wm2[t]; }
  if (t == 0) b2s[0] = bm2[0];
  __syncthreads();
  const int e = (bid - 1568) * 256 + t;
  if (e >= NE) return;
  f32x4 r0 = *(const f32x4*)(ea + e * 16);
  f32x4 r1 = *(const f32x4*)(ea + e * 16 + 4);
  f32x4 r2 = *(const f32x4*)(ea + e * 16 + 8);
  f32x4 r3 = *(const f32x4*)(ea + e * 16 + 12);
  const f32x4* bv = (const f32x4*)b1;
  f32x4 h0 = bv[0], h1 = bv[1], h2 = bv[2], h3 = bv[3];
  f32x4 h4 = bv[4], h5 = bv[5], h6 = bv[6], h7 = bv[7];
  const f32x4* wv = (const f32x4*)w1;
  mlp4(r0[0], r0[1], r0[2], r0[3], wv, h0, h1, h2, h3, h4, h5, h6, h7);
  mlp4(r1[0], r1[1], r1[2], r1[3], wv + 32, h0, h1, h2, h3, h4, h5, h6, h7);
  mlp4(r2[0], r2[1], r2[2], r2[3], wv + 64, h0, h1, h2, h3, h4, h5, h6, h7);
  mlp4(r3[0], r3[1], r3[2], r3[3], wv + 96, h0, h1, h2, h3, h4, h5, h6, h7);
  const f32x4* w2v = (const f32x4*)w2;
  float s = b2s[0];
  s += rdot(h0, w2v[0]) + rdot(h1, w2v[1]) + rdot(h2, w2v[2]) + rdot(h3, w2v[3]);
  s += rdot(h4, w2v[4]) + rdot(h5, w2v[5]) + rdot(h6, w2v[6]) + rdot(h7, w2v[7]);
  const float sp = (s > 0.0f) ? (s + log1pf(expf(-s))) : log1pf(expf(s));
  uint2 p;
  p.x = (unsigned)ei[NE + e];
  p.y = __float_as_uint(sp);
  colw[start[ei[e]] + rank[e]] = p;
}

// ---------------- combine GEMM wrapper (reads aggb directly; norm folded into weights)
__global__ __launch_bounds__(256, 3) void gemm_combine(
    const unsigned short* __restrict__ aggb, const unsigned short* __restrict__ xbf,
    const unsigned short* __restrict__ WT1, const unsigned short* __restrict__ WT0,
    const float* __restrict__ bias1, const float* __restrict__ bias0,
    const int* __restrict__ mask, float* __restrict__ out) {
  __shared__ __align__(16) unsigned short SH[128 * 64 + 64 * 64 + 64 * 64];
  gemm_tile<512, true, false>(SH, blockIdx.x, aggb, xbf, WT1, WT0, bias1, bias0, mask, out);
}

// ---------------- pull aggregation (R3-proven: one wave/row, 8 edges in flight; NO stats)
#define EDGE(u, wgt) do { \
  dsum += wgt; \
  acc[0] = fmaf(wgt, __uint_as_float(u.x << 16), acc[0]); \
  acc[1] = fmaf(wgt, __uint_as_float(u.x & 0xffff0000u), acc[1]); \
  acc[2] = fmaf(wgt, __uint_as_float(u.y << 16), acc[2]); \
  acc[3] = fmaf(wgt, __uint_as_float(u.y & 0xffff0000u), acc[3]); \
} while (0)

__global__ __launch_bounds__(256) void aggregate_kernel(
    const int* __restrict__ start, const int* __restrict__ cnt,
    const uint2* __restrict__ colw,
    const unsigned short* __restrict__ xmb, unsigned short* __restrict__ aggb) {
  const int wave = threadIdx.x >> 6, lane = threadIdx.x & 63;
  const int row = blockIdx.x * 4 + wave;
  const int s = start[row];
  const int c = cnt[row];
  const int choff = lane * 4;
  f32x4 acc = (f32x4)(0.0f);
  float dsum = 0.0f;
  int i = 0;
  for (; i + 8 <= c; i += 8) {  // 8 edges in flight
    uint2 cw0 = colw[s + i],     cw1 = colw[s + i + 1];
    uint2 cw2 = colw[s + i + 2], cw3 = colw[s + i + 3];
    uint2 cw4 = colw[s + i + 4], cw5 = colw[s + i + 5];
    uint2 cw6 = colw[s + i + 6], cw7 = colw[s + i + 7];
    uint2 u0 = *(const uint2*)(xmb + (size_t)cw0.x * 256 + choff);
    uint2 u1 = *(const uint2*)(xmb + (size_t)cw1.x * 256 + choff);
    uint2 u2 = *(const uint2*)(xmb + (size_t)cw2.x * 256 + choff);
    uint2 u3 = *(const uint2*)(xmb + (size_t)cw3.x * 256 + choff);
    uint2 u4 = *(const uint2*)(xmb + (size_t)cw4.x * 256 + choff);
    uint2 u5 = *(const uint2*)(xmb + (size_t)cw5.x * 256 + choff);
    uint2 u6 = *(const uint2*)(xmb + (size_t)cw6.x * 256 + choff);
    uint2 u7 = *(const uint2*)(xmb + (size_t)cw7.x * 256 + choff);
    EDGE(u0, __uint_as_float(cw0.y));
    EDGE(u1, __uint_as_float(cw1.y));
    EDGE(u2, __uint_as_float(cw2.y));
    EDGE(u3, __uint_as_float(cw3.y));
    EDGE(u4, __uint_as_float(cw4.y));
    EDGE(u5, __uint_as_float(cw5.y));
    EDGE(u6, __uint_as_float(cw6.y));
    EDGE(u7, __uint_as_float(cw7.y));
  }
  for (; i + 4 <= c; i += 4) {
    uint2 cw0 = colw[s + i],     cw1 = colw[s + i + 1];
    uint2 cw2 = colw[s + i + 2], cw3 = colw[s + i + 3];
    uint2 u0 = *(const uint2*)(xmb + (size_t)cw0.x * 256 + choff);
    uint2 u1 = *(const uint2*)(xmb + (size_t)cw1.x * 256 + choff);
    uint2 u2 = *(const uint2*)(xmb + (size_t)cw2.x * 256 + choff);
    uint2 u3 = *(const uint2*)(xmb + (size_t)cw3.x * 256 + choff);
    EDGE(u0, __uint_as_float(cw0.y));
    EDGE(u1, __uint_as_float(cw1.y));
    EDGE(u2, __uint_as_float(cw2.y));
    EDGE(u3, __uint_as_float(cw3.y));
  }
  for (; i < c; i++) {
    uint2 cw0 = colw[s + i];
    uint2 u0 = *(const uint2*)(xmb + (size_t)cw0.x * 256 + choff);
    EDGE(u0, __uint_as_float(cw0.y));
  }
  float d = (dsum < 0.5f) ? dsum + 1.0f : dsum;
  const float inv = 1.0f / d;
  unsigned short o[4];
#pragma unroll
  for (int j = 0; j < 4; j++) o[j] = f2bf(acc[j] * inv);
  *(uint2*)(aggb + (size_t)row * 256 + choff) = *(const uint2*)o;
}

// ---------------- per-channel sums for GraphNorm (separate pass: depth-250 atomic chains)
__global__ __launch_bounds__(256) void stats_kernel(
    const unsigned short* __restrict__ aggb, float* __restrict__ S1, float* __restrict__ S2) {
  const int c = threadIdx.x;
  const int r0 = blockIdx.x * 200;
  float s1 = 0.0f, s2 = 0.0f;
  for (int r = 0; r < 200; r++) {
    float v = bfu2f(aggb[(size_t)(r0 + r) * 256 + c]);
    s1 += v;
    s2 = fmaf(v, v, s2);
  }
  unsafeAtomicAdd(&S1[c], s1);
  unsafeAtomicAdd(&S2[c], s2);
}

// ---------------- fold GraphNorm into combine weights/biases:
// WTc'[n][k<256] = sc_k * WTc[n][k];  bias'[n] = bc[n] + sum_k sh_k * Wc[k][n] (fp32)
__global__ __launch_bounds__(256) void fold_kernel(
    const float* __restrict__ S1, const float* __restrict__ S2,
    const float* __restrict__ gnw, const float* __restrict__ gnb,
    const float* __restrict__ gna,
    const float* __restrict__ Wc1, const float* __restrict__ Wc0,
    const float* __restrict__ bc1, const float* __restrict__ bc0,
    unsigned short* __restrict__ WTc1, unsigned short* __restrict__ WTc0,
    float* __restrict__ b1f, float* __restrict__ b0f) {
  __shared__ float r1[256];
  __shared__ float r0[256];
  const int n = blockIdx.x, t = threadIdx.x;
  const float inv_n = 1.0f / (float)NN;
  const float mean = S1[t] * inv_n;
  const float ex2 = S2[t] * inv_n;
  const float am = gna[t] * mean;
  const float var = ex2 - 2.0f * am * mean + am * am;
  const float sc = gnw[t] * rsqrtf(var + 1e-5f);
  const float sh = gnb[t] - sc * am;
  const float w1 = bfu2f(WTc1[n * 512 + t]);
  WTc1[n * 512 + t] = f2bf(w1 * sc);
  const float w0 = bfu2f(WTc0[n * 512 + t]);
  WTc0[n * 512 + t] = f2bf(w0 * sc);
  r1[t] = sh * Wc1[t * 256 + n];
  r0[t] = sh * Wc0[t * 256 + n];
  __syncthreads();
  for (int off = 128; off > 0; off >>= 1) {
    if (t < off) { r1[t] += r1[t + off]; r0[t] += r0[t + off]; }
    __syncthreads();
  }
  if (t == 0) {
    b1f[n] = bc1[n] + r1[0];
    b0f[n] = bc0[n] + r0[0];
  }
}

extern "C" void kernel_launch(void* const* d_in, const int* in_sizes, int n_in,
                              void* d_out, int out_size, void* d_ws, size_t ws_size,
                              hipStream_t stream) {
  (void)in_sizes; (void)n_in; (void)out_size; (void)ws_size;
  const float* x   = (const float*)d_in[0];
  const int*   ei  = (const int*)d_in[1];
  const int*   msk = (const int*)d_in[3];
  const float* ea  = (const float*)d_in[4];
  const float* Wt0 = (const float*)d_in[5];
  const float* bt0 = (const float*)d_in[6];
  const float* Wt1 = (const float*)d_in[7];
  const float* bt1 = (const float*)d_in[8];
  const float* Wc0 = (const float*)d_in[9];
  const float* bc0 = (const float*)d_in[10];
  const float* Wc1 = (const float*)d_in[11];
  const float* bc1 = (const float*)d_in[12];
  const float* gnw = (const float*)d_in[13];
  const float* gnb = (const float*)d_in[14];
  const float* gna = (const float*)d_in[15];
  const float* Wm1 = (const float*)d_in[16];
  const float* bm1 = (const float*)d_in[17];
  const float* Wm2 = (const float*)d_in[18];
  const float* bm2 = (const float*)d_in[19];

  char* ws = (char*)d_ws;
  int* cnt      = (int*)ws;
  int* startA   = (int*)(ws + OFF_START);
  float* S1     = (float*)(ws + OFF_S1);
  float* S2     = (float*)(ws + OFF_S2);
  unsigned short* WTt1 = (unsigned short*)(ws + OFF_WTT1);
  unsigned short* WTt0 = (unsigned short*)(ws + OFF_WTT0);
  unsigned short* WTc1 = (unsigned short*)(ws + OFF_WTC1);
  unsigned short* WTc0 = (unsigned short*)(ws + OFF_WTC0);
  int* rankA    = (int*)(ws + OFF_RANK);
  uint2* colw   = (uint2*)(ws + OFF_COLW);
  unsigned short* xmb  = (unsigned short*)(ws + OFF_XMB);
  unsigned short* aggb = (unsigned short*)(ws + OFF_AGG);
  unsigned short* xbf  = (unsigned short*)(ws + OFF_XBF);
  float* b1f = (float*)(ws + OFF_B1F);  // reuses xmb region (dead after aggregate)
  float* b0f = (float*)(ws + OFF_B0F);

  hipMemsetAsync(ws, 0, 404480, stream);  // cnt + start + S1/S2

  prep_kernel<<<9803, 256, 0, stream>>>(x, xbf, ei, cnt, rankA,
                                        Wt1, Wt0, Wc1, Wc0,
                                        WTt1, WTt0, WTc1, WTc0, aggb);
  scan_all<<<196, 256, 0, stream>>>(cnt, startA);
  midk<<<4693, 256, 0, stream>>>(xbf, WTt1, WTt0, bt1, bt0, msk, xmb,
                                 ea, Wm1, bm1, Wm2, bm2, ei, startA, rankA, colw);
  aggregate_kernel<<<12500, 256, 0, stream>>>(startA, cnt, colw, xmb, aggb);
  stats_kernel<<<250, 256, 0, stream>>>(aggb, S1, S2);
  fold_kernel<<<256, 256, 0, stream>>>(S1, S2, gnw, gnb, gna, Wc1, Wc0, bc1, bc0,
                                       WTc1, WTc0, b1f, b0f);
  gemm_combine<<<1568, 256, 0, stream>>>(aggb, xbf, WTc1, WTc0, b1f, b0f,
                                         msk, (float*)d_out);
}